// Round 1
// baseline (510.910 us; speedup 1.0000x reference)
//
#include <hip/hip_runtime.h>
#include <cstdint>
#include <cstddef>

#define N_NODES 50000
#define BN_EPS 1e-5f

// ---------------- degree / CSR build ----------------

__global__ __launch_bounds__(256) void k_init_deg(float* deg) {
  int i = blockIdx.x * 256 + threadIdx.x;
  if (i < N_NODES) deg[i] = 1.0f;  // self-loop weight
}

__global__ __launch_bounds__(256) void k_hist(const int* __restrict__ src,
    const int* __restrict__ dst, const float* __restrict__ ew, int E,
    float* __restrict__ deg, int* __restrict__ count) {
  int e = blockIdx.x * 256 + threadIdx.x;
  if (e < E) {
    int d = dst[e];
    atomicAdd(&deg[d], ew[e]);
    atomicAdd(&count[d], 1);
  }
}

__global__ __launch_bounds__(256) void k_dinv(float* deg) {
  int i = blockIdx.x * 256 + threadIdx.x;
  if (i < N_NODES) {
    float d = deg[i];
    deg[i] = d > 0.f ? rsqrtf(d) : 0.f;  // in-place: deg -> dinv
  }
}

__global__ __launch_bounds__(1024) void k_scan_chunk(const int* __restrict__ in,
    int* __restrict__ incl, int* __restrict__ bsums, int n) {
  __shared__ int tmp[1024];
  int gid = blockIdx.x * 1024 + threadIdx.x;
  int v = (gid < n) ? in[gid] : 0;
  tmp[threadIdx.x] = v;
  __syncthreads();
  for (int off = 1; off < 1024; off <<= 1) {
    int a = (threadIdx.x >= off) ? tmp[threadIdx.x - off] : 0;
    __syncthreads();
    tmp[threadIdx.x] += a;
    __syncthreads();
  }
  if (gid < n) incl[gid] = tmp[threadIdx.x];
  if (threadIdx.x == 1023) bsums[blockIdx.x] = tmp[1023];
}

__global__ void k_scan_tops(int* bsums, int nb) {
  if (threadIdx.x == 0 && blockIdx.x == 0) {
    int acc = 0;
    for (int i = 0; i < nb; ++i) { int t = bsums[i]; bsums[i] = acc; acc += t; }
  }
}

__global__ __launch_bounds__(256) void k_scan_fin(const int* __restrict__ incl,
    const int* __restrict__ count, const int* __restrict__ bsums,
    int* __restrict__ start, int n) {
  int gid = blockIdx.x * 256 + threadIdx.x;
  if (gid < n) {
    int inc = incl[gid];
    start[gid] = inc - count[gid] + bsums[gid >> 10];
    if (gid == n - 1) start[n] = inc + bsums[gid >> 10];
  }
}

__global__ __launch_bounds__(256) void k_fill(const int* __restrict__ src,
    const int* __restrict__ dst, const float* __restrict__ ew, int E,
    const float* __restrict__ dinv, const int* __restrict__ start,
    int* __restrict__ cursor, int* __restrict__ csr_src, float* __restrict__ csr_w) {
  int e = blockIdx.x * 256 + threadIdx.x;
  if (e < E) {
    int s = src[e], d = dst[e];
    int p = start[d] + atomicAdd(&cursor[d], 1);
    csr_src[p] = s;
    csr_w[p] = dinv[s] * ew[e] * dinv[d];
  }
}

// ---------------- GEMM: out[N,Fout] = X[N,128] @ W[128,Fout] ----------------

__global__ __launch_bounds__(256) void k_gemm(const float* __restrict__ X,
    const float* __restrict__ W, float* __restrict__ out, int Fout) {
  __shared__ float Xs[64][68];
  __shared__ float Ws[64][68];
  int tid = threadIdx.x;
  int r0 = blockIdx.x * 64;
  int c0 = blockIdx.y * 64;
  int ty = tid >> 4, tx = tid & 15;
  float acc[4][4] = {};
  for (int k0 = 0; k0 < 128; k0 += 64) {
    // stage X chunk [64 rows][64 k]
    #pragma unroll
    for (int j = 0; j < 4; ++j) {
      int f4 = tid + j * 256;         // 0..1023
      int row = f4 >> 4;              // 0..63
      int c4 = (f4 & 15) * 4;         // 0..60
      float4 v = make_float4(0.f, 0.f, 0.f, 0.f);
      int gr = r0 + row;
      if (gr < N_NODES)
        v = *reinterpret_cast<const float4*>(&X[(size_t)gr * 128 + k0 + c4]);
      *reinterpret_cast<float4*>(&Xs[row][c4]) = v;
    }
    // stage W chunk [64 k][64 cols]
    #pragma unroll
    for (int j = 0; j < 4; ++j) {
      int f4 = tid + j * 256;
      int k = f4 >> 4;
      int c4 = (f4 & 15) * 4;
      int gc = c0 + c4;
      float4 v = make_float4(0.f, 0.f, 0.f, 0.f);
      if (gc + 3 < Fout)
        v = *reinterpret_cast<const float4*>(&W[(size_t)(k0 + k) * Fout + gc]);
      *reinterpret_cast<float4*>(&Ws[k][c4]) = v;
    }
    __syncthreads();
    #pragma unroll 16
    for (int k = 0; k < 64; ++k) {
      float4 wv = *reinterpret_cast<const float4*>(&Ws[k][tx * 4]);
      float xv0 = Xs[ty * 4 + 0][k];
      float xv1 = Xs[ty * 4 + 1][k];
      float xv2 = Xs[ty * 4 + 2][k];
      float xv3 = Xs[ty * 4 + 3][k];
      acc[0][0] += xv0 * wv.x; acc[0][1] += xv0 * wv.y; acc[0][2] += xv0 * wv.z; acc[0][3] += xv0 * wv.w;
      acc[1][0] += xv1 * wv.x; acc[1][1] += xv1 * wv.y; acc[1][2] += xv1 * wv.z; acc[1][3] += xv1 * wv.w;
      acc[2][0] += xv2 * wv.x; acc[2][1] += xv2 * wv.y; acc[2][2] += xv2 * wv.z; acc[2][3] += xv2 * wv.w;
      acc[3][0] += xv3 * wv.x; acc[3][1] += xv3 * wv.y; acc[3][2] += xv3 * wv.z; acc[3][3] += xv3 * wv.w;
    }
    __syncthreads();
  }
  #pragma unroll
  for (int i = 0; i < 4; ++i) {
    int gr = r0 + ty * 4 + i;
    if (gr >= N_NODES) continue;
    #pragma unroll
    for (int j = 0; j < 4; ++j) {
      int gc = c0 + tx * 4 + j;
      if (gc < Fout) out[(size_t)gr * Fout + gc] = acc[i][j];
    }
  }
}

// ---------------- aggregation (gather over CSR) ----------------

__global__ __launch_bounds__(256) void k_agg128(const float* __restrict__ xw,
    const float* __restrict__ bias, const float* __restrict__ dinv,
    const int* __restrict__ start, const int* __restrict__ csr_src,
    const float* __restrict__ csr_w, float* __restrict__ out) {
  int lane = threadIdx.x & 31;                 // float4 index 0..31
  int node = blockIdx.x * 8 + (threadIdx.x >> 5);
  if (node >= N_NODES) return;
  const float4* xwv = (const float4*)xw;
  float4 acc = ((const float4*)bias)[lane];
  float di = dinv[node];
  float w0 = di * di;
  float4 sv = xwv[(size_t)node * 32 + lane];
  acc.x += w0 * sv.x; acc.y += w0 * sv.y; acc.z += w0 * sv.z; acc.w += w0 * sv.w;
  int e0 = start[node], e1 = start[node + 1];
  for (int e = e0; e < e1; ++e) {
    int s = csr_src[e];
    float w = csr_w[e];
    float4 v = xwv[(size_t)s * 32 + lane];
    acc.x += w * v.x; acc.y += w * v.y; acc.z += w * v.z; acc.w += w * v.w;
  }
  ((float4*)out)[(size_t)node * 32 + lane] = acc;
}

__global__ __launch_bounds__(256) void k_agg40(const float* __restrict__ xw,
    const float* __restrict__ bias, const float* __restrict__ dinv,
    const int* __restrict__ start, const int* __restrict__ csr_src,
    const float* __restrict__ csr_w, float* __restrict__ out) {
  int lane = threadIdx.x & 15;                 // float4 index, valid < 10
  int node = blockIdx.x * 16 + (threadIdx.x >> 4);
  if (node >= N_NODES || lane >= 10) return;
  const float4* xwv = (const float4*)xw;
  float4 acc = ((const float4*)bias)[lane];
  float di = dinv[node];
  float w0 = di * di;
  float4 sv = xwv[(size_t)node * 10 + lane];
  acc.x += w0 * sv.x; acc.y += w0 * sv.y; acc.z += w0 * sv.z; acc.w += w0 * sv.w;
  int e0 = start[node], e1 = start[node + 1];
  for (int e = e0; e < e1; ++e) {
    int s = csr_src[e];
    float w = csr_w[e];
    float4 v = xwv[(size_t)s * 10 + lane];
    acc.x += w * v.x; acc.y += w * v.y; acc.z += w * v.z; acc.w += w * v.w;
  }
  ((float4*)out)[(size_t)node * 10 + lane] = acc;
}

// ---------------- batch norm + relu ----------------

__global__ __launch_bounds__(256) void k_bnstats(const float* __restrict__ x,
    float* __restrict__ sums) {
  int f = threadIdx.x & 127;
  int half = threadIdx.x >> 7;
  float s = 0.f, sq = 0.f;
  for (int row = blockIdx.x * 2 + half; row < N_NODES; row += gridDim.x * 2) {
    float v = x[(size_t)row * 128 + f];
    s += v; sq += v * v;
  }
  __shared__ float ls[256], lq[256];
  ls[threadIdx.x] = s; lq[threadIdx.x] = sq;
  __syncthreads();
  if (half == 0) {
    s += ls[threadIdx.x + 128];
    sq += lq[threadIdx.x + 128];
    atomicAdd(&sums[f], s);
    atomicAdd(&sums[128 + f], sq);
  }
}

__global__ void k_bnfinal(const float* __restrict__ sums,
    const float* __restrict__ gamma, const float* __restrict__ beta,
    float* __restrict__ ssb) {
  int f = threadIdx.x;  // 128 threads
  float inv_n = 1.0f / (float)N_NODES;
  float mu = sums[f] * inv_n;
  float var = sums[128 + f] * inv_n - mu * mu;
  if (var < 0.f) var = 0.f;
  float scale = gamma[f] * rsqrtf(var + BN_EPS);
  ssb[f] = scale;
  ssb[128 + f] = beta[f] - mu * scale;
}

__global__ __launch_bounds__(256) void k_bnapply(float* __restrict__ x,
    const float* __restrict__ ssb) {
  int idx = blockIdx.x * 256 + threadIdx.x;   // float4 index over N*32
  int f4 = idx & 31;
  float4 sc = ((const float4*)ssb)[f4];
  float4 sh = ((const float4*)(ssb + 128))[f4];
  float4 v = ((const float4*)x)[idx];
  v.x = fmaxf(0.f, v.x * sc.x + sh.x);
  v.y = fmaxf(0.f, v.y * sc.y + sh.y);
  v.z = fmaxf(0.f, v.z * sc.z + sh.z);
  v.w = fmaxf(0.f, v.w * sc.w + sh.w);
  ((float4*)x)[idx] = v;
}

// ---------------- log_softmax over 40 classes ----------------

__global__ __launch_bounds__(256) void k_logsm(float* __restrict__ io) {
  int lane = threadIdx.x & 63;
  int node = blockIdx.x * 4 + (threadIdx.x >> 6);
  if (node >= N_NODES) return;
  float v = (lane < 40) ? io[(size_t)node * 40 + lane] : -1e30f;
  float m = v;
  #pragma unroll
  for (int off = 32; off >= 1; off >>= 1) m = fmaxf(m, __shfl_xor(m, off));
  float e = (lane < 40) ? expf(v - m) : 0.f;
  float ssum = e;
  #pragma unroll
  for (int off = 32; off >= 1; off >>= 1) ssum += __shfl_xor(ssum, off);
  if (lane < 40) io[(size_t)node * 40 + lane] = v - m - logf(ssum);
}

// ---------------- launch ----------------

extern "C" void kernel_launch(void* const* d_in, const int* in_sizes, int n_in,
                              void* d_out, int out_size, void* d_ws, size_t ws_size,
                              hipStream_t stream) {
  const float* x   = (const float*)d_in[0];
  const int*   ei  = (const int*)d_in[1];
  const float* ew  = (const float*)d_in[2];
  const float* W1  = (const float*)d_in[3];
  const float* b1  = (const float*)d_in[4];
  const float* g1  = (const float*)d_in[5];
  const float* be1 = (const float*)d_in[6];
  const float* W2  = (const float*)d_in[7];
  const float* b2  = (const float*)d_in[8];
  const float* g2  = (const float*)d_in[9];
  const float* be2 = (const float*)d_in[10];
  const float* W3  = (const float*)d_in[11];
  const float* b3  = (const float*)d_in[12];
  float* out = (float*)d_out;
  int E = in_sizes[2];
  const int* src = ei;
  const int* dst = ei + E;

  char* p = (char*)d_ws;
  auto alloc = [&](size_t bytes) {
    char* r = p; p += (bytes + 255) & ~(size_t)255; return r;
  };
  float* deg   = (float*)alloc((size_t)N_NODES * 4);   // becomes dinv
  int*   count = (int*)  alloc((size_t)N_NODES * 4);
  int*   cursor= (int*)  alloc((size_t)N_NODES * 4);
  int*   incl  = (int*)  alloc((size_t)N_NODES * 4);
  int*   bsums = (int*)  alloc(64 * 4);
  int*   startA= (int*)  alloc((size_t)(N_NODES + 1) * 4);
  int*   csrs  = (int*)  alloc((size_t)E * 4);
  float* csrw  = (float*)alloc((size_t)E * 4);
  float* stats = (float*)alloc(256 * 4);
  float* ssb   = (float*)alloc(256 * 4);
  float* bufA  = (float*)alloc((size_t)N_NODES * 128 * 4);
  float* bufB  = (float*)alloc((size_t)N_NODES * 128 * 4);

  int nblkN = (N_NODES + 255) / 256;             // 196
  int nblkE = (E + 255) / 256;
  int nb = (N_NODES + 1023) / 1024;              // 49

  hipMemsetAsync(count, 0, (size_t)N_NODES * 4, stream);
  hipMemsetAsync(cursor, 0, (size_t)N_NODES * 4, stream);
  k_init_deg<<<nblkN, 256, 0, stream>>>(deg);
  k_hist<<<nblkE, 256, 0, stream>>>(src, dst, ew, E, deg, count);
  k_dinv<<<nblkN, 256, 0, stream>>>(deg);
  k_scan_chunk<<<nb, 1024, 0, stream>>>(count, incl, bsums, N_NODES);
  k_scan_tops<<<1, 64, 0, stream>>>(bsums, nb);
  k_scan_fin<<<nblkN, 256, 0, stream>>>(incl, count, bsums, startA, N_NODES);
  k_fill<<<nblkE, 256, 0, stream>>>(src, dst, ew, E, deg, startA, cursor, csrs, csrw);

  dim3 gemmGrid((N_NODES + 63) / 64, 2);
  dim3 gemmGrid3((N_NODES + 63) / 64, 1);

  // layer 1
  k_gemm<<<gemmGrid, 256, 0, stream>>>(x, W1, bufA, 128);
  k_agg128<<<(N_NODES + 7) / 8, 256, 0, stream>>>(bufA, b1, deg, startA, csrs, csrw, bufB);
  hipMemsetAsync(stats, 0, 256 * 4, stream);
  k_bnstats<<<256, 256, 0, stream>>>(bufB, stats);
  k_bnfinal<<<1, 128, 0, stream>>>(stats, g1, be1, ssb);
  k_bnapply<<<(N_NODES * 32 + 255) / 256, 256, 0, stream>>>(bufB, ssb);

  // layer 2
  k_gemm<<<gemmGrid, 256, 0, stream>>>(bufB, W2, bufA, 128);
  k_agg128<<<(N_NODES + 7) / 8, 256, 0, stream>>>(bufA, b2, deg, startA, csrs, csrw, bufB);
  hipMemsetAsync(stats, 0, 256 * 4, stream);
  k_bnstats<<<256, 256, 0, stream>>>(bufB, stats);
  k_bnfinal<<<1, 128, 0, stream>>>(stats, g2, be2, ssb);
  k_bnapply<<<(N_NODES * 32 + 255) / 256, 256, 0, stream>>>(bufB, ssb);

  // layer 3
  k_gemm<<<gemmGrid3, 256, 0, stream>>>(bufB, W3, bufA, 40);
  k_agg40<<<(N_NODES + 15) / 16, 256, 0, stream>>>(bufA, b3, deg, startA, csrs, csrw, out);
  k_logsm<<<(N_NODES + 3) / 4, 256, 0, stream>>>(out);
}

// Round 2
// 428.152 us; speedup vs baseline: 1.1933x; 1.1933x over previous
//
#include <hip/hip_runtime.h>
#include <cstdint>
#include <cstddef>

#define N_NODES 50000
#define BN_EPS 1e-5f

// ---------------- helpers ----------------

__device__ inline unsigned short bf16rn(float f) {
  unsigned int u = __float_as_uint(f);
  u += 0x7fffu + ((u >> 16) & 1u);
  return (unsigned short)(u >> 16);
}

__device__ inline float4 bf4(uint2 v) {
  float4 r;
  r.x = __uint_as_float(v.x << 16);
  r.y = __uint_as_float(v.x & 0xffff0000u);
  r.z = __uint_as_float(v.y << 16);
  r.w = __uint_as_float(v.y & 0xffff0000u);
  return r;
}

// ---------------- CSR build ----------------

__global__ __launch_bounds__(256) void k_count(const int* __restrict__ dst, int E,
                                               int* __restrict__ count) {
  int e = blockIdx.x * 256 + threadIdx.x;
  if (e < E) atomicAdd(&count[dst[e]], 1);
}

__global__ __launch_bounds__(1024) void k_scan_chunk(const int* __restrict__ in,
    int* __restrict__ incl, int* __restrict__ bsums, int n) {
  __shared__ int tmp[1024];
  int gid = blockIdx.x * 1024 + threadIdx.x;
  int v = (gid < n) ? in[gid] : 0;
  tmp[threadIdx.x] = v;
  __syncthreads();
  for (int off = 1; off < 1024; off <<= 1) {
    int a = (threadIdx.x >= off) ? tmp[threadIdx.x - off] : 0;
    __syncthreads();
    tmp[threadIdx.x] += a;
    __syncthreads();
  }
  if (gid < n) incl[gid] = tmp[threadIdx.x];
  if (threadIdx.x == 1023) bsums[blockIdx.x] = tmp[1023];
}

__global__ void k_scan_tops(int* bsums, int nb) {
  if (threadIdx.x == 0 && blockIdx.x == 0) {
    int acc = 0;
    for (int i = 0; i < nb; ++i) { int t = bsums[i]; bsums[i] = acc; acc += t; }
  }
}

__global__ __launch_bounds__(256) void k_scan_fin(const int* __restrict__ incl,
    const int* __restrict__ count, const int* __restrict__ bsums,
    int* __restrict__ start, int n) {
  int gid = blockIdx.x * 256 + threadIdx.x;
  if (gid < n) {
    int inc = incl[gid];
    start[gid] = inc - count[gid] + bsums[gid >> 10];
    if (gid == n - 1) start[n] = inc + bsums[gid >> 10];
  }
}

__global__ __launch_bounds__(256) void k_fill(const int* __restrict__ src,
    const int* __restrict__ dst, const float* __restrict__ ew, int E,
    const int* __restrict__ start, int* __restrict__ cursor,
    int2* __restrict__ csr) {
  int e = blockIdx.x * 256 + threadIdx.x;
  if (e < E) {
    int d = dst[e];
    int p = start[d] + atomicAdd(&cursor[d], 1);
    csr[p] = make_int2(src[e], __float_as_int(ew[e]));
  }
}

// per node: deg = 1 + sum(ew over bucket); dinv = rsqrt(deg)
__global__ __launch_bounds__(256) void k_degdinv(const int2* __restrict__ csr,
    const int* __restrict__ start, float* __restrict__ dinv) {
  int lane = threadIdx.x & 15;
  int node = blockIdx.x * 16 + (threadIdx.x >> 4);
  if (node >= N_NODES) return;
  int e0 = start[node], e1 = start[node + 1];
  float s = 0.f;
  for (int e = e0 + lane; e < e1; e += 16) s += __int_as_float(csr[e].y);
  #pragma unroll
  for (int off = 8; off >= 1; off >>= 1) s += __shfl_xor(s, off, 16);
  if (lane == 0) dinv[node] = rsqrtf(1.0f + s);
}

// ---------------- GEMM: out16[N,Fout] = act(X)[N,128] @ W[128,Fout] ----------------
// if ssb != null: act(x)_f = max(0, x_f * ssb[f] + ssb[128+f])  (fused BN+ReLU)

__global__ __launch_bounds__(256) void k_gemm(const float* __restrict__ X,
    const float* __restrict__ W, const float* __restrict__ ssb,
    unsigned short* __restrict__ out16, int Fout) {
  __shared__ float Xs[64][68];
  __shared__ float Ws[64][68];
  int tid = threadIdx.x;
  int r0 = blockIdx.x * 64;
  int c0 = blockIdx.y * 64;
  int ty = tid >> 4, tx = tid & 15;
  float acc[4][4] = {};
  for (int k0 = 0; k0 < 128; k0 += 64) {
    #pragma unroll
    for (int j = 0; j < 4; ++j) {
      int f4 = tid + j * 256;
      int row = f4 >> 4;
      int c4 = (f4 & 15) * 4;
      float4 v = make_float4(0.f, 0.f, 0.f, 0.f);
      int gr = r0 + row;
      if (gr < N_NODES)
        v = *reinterpret_cast<const float4*>(&X[(size_t)gr * 128 + k0 + c4]);
      if (ssb) {
        float4 sc = reinterpret_cast<const float4*>(ssb)[(k0 + c4) >> 2];
        float4 sh = reinterpret_cast<const float4*>(ssb + 128)[(k0 + c4) >> 2];
        v.x = fmaxf(0.f, v.x * sc.x + sh.x);
        v.y = fmaxf(0.f, v.y * sc.y + sh.y);
        v.z = fmaxf(0.f, v.z * sc.z + sh.z);
        v.w = fmaxf(0.f, v.w * sc.w + sh.w);
      }
      *reinterpret_cast<float4*>(&Xs[row][c4]) = v;
    }
    #pragma unroll
    for (int j = 0; j < 4; ++j) {
      int f4 = tid + j * 256;
      int k = f4 >> 4;
      int c4 = (f4 & 15) * 4;
      int gc = c0 + c4;
      float4 v = make_float4(0.f, 0.f, 0.f, 0.f);
      if (gc + 3 < Fout)
        v = *reinterpret_cast<const float4*>(&W[(size_t)(k0 + k) * Fout + gc]);
      *reinterpret_cast<float4*>(&Ws[k][c4]) = v;
    }
    __syncthreads();
    #pragma unroll 16
    for (int k = 0; k < 64; ++k) {
      float4 wv = *reinterpret_cast<const float4*>(&Ws[k][tx * 4]);
      float xv0 = Xs[ty * 4 + 0][k];
      float xv1 = Xs[ty * 4 + 1][k];
      float xv2 = Xs[ty * 4 + 2][k];
      float xv3 = Xs[ty * 4 + 3][k];
      acc[0][0] += xv0 * wv.x; acc[0][1] += xv0 * wv.y; acc[0][2] += xv0 * wv.z; acc[0][3] += xv0 * wv.w;
      acc[1][0] += xv1 * wv.x; acc[1][1] += xv1 * wv.y; acc[1][2] += xv1 * wv.z; acc[1][3] += xv1 * wv.w;
      acc[2][0] += xv2 * wv.x; acc[2][1] += xv2 * wv.y; acc[2][2] += xv2 * wv.z; acc[2][3] += xv2 * wv.w;
      acc[3][0] += xv3 * wv.x; acc[3][1] += xv3 * wv.y; acc[3][2] += xv3 * wv.z; acc[3][3] += xv3 * wv.w;
    }
    __syncthreads();
  }
  #pragma unroll
  for (int i = 0; i < 4; ++i) {
    int gr = r0 + ty * 4 + i;
    if (gr >= N_NODES) continue;
    int gc = c0 + tx * 4;
    if (gc + 3 < Fout) {
      ushort4 o;
      o.x = bf16rn(acc[i][0]);
      o.y = bf16rn(acc[i][1]);
      o.z = bf16rn(acc[i][2]);
      o.w = bf16rn(acc[i][3]);
      *reinterpret_cast<ushort4*>(&out16[(size_t)gr * Fout + gc]) = o;
    }
  }
}

// ---------------- aggregation (gather over CSR, bf16 rows, on-the-fly norm) ----------------

__global__ __launch_bounds__(256) void k_agg128b(const unsigned short* __restrict__ xw,
    const float* __restrict__ bias, const float* __restrict__ dinv,
    const int* __restrict__ start, const int2* __restrict__ csr,
    float* __restrict__ out) {
  int lane = threadIdx.x & 31;                 // uint2 index 0..31 (4 bf16 each)
  int node = blockIdx.x * 8 + (threadIdx.x >> 5);
  if (node >= N_NODES) return;
  const uint2* rows = (const uint2*)xw;        // row stride 32 uint2
  float di = dinv[node];
  float w0 = di * di;
  float4 bb = ((const float4*)bias)[lane];
  float4 sv = bf4(rows[(size_t)node * 32 + lane]);
  float4 acc;
  acc.x = bb.x + w0 * sv.x; acc.y = bb.y + w0 * sv.y;
  acc.z = bb.z + w0 * sv.z; acc.w = bb.w + w0 * sv.w;
  int e0 = start[node], e1 = start[node + 1];
  for (int e = e0; e < e1; ++e) {
    int2 c = csr[e];
    float w = __int_as_float(c.y) * dinv[c.x] * di;
    float4 v = bf4(rows[(size_t)c.x * 32 + lane]);
    acc.x += w * v.x; acc.y += w * v.y; acc.z += w * v.z; acc.w += w * v.w;
  }
  ((float4*)out)[(size_t)node * 32 + lane] = acc;
}

__global__ __launch_bounds__(256) void k_agg40b(const unsigned short* __restrict__ xw,
    const float* __restrict__ bias, const float* __restrict__ dinv,
    const int* __restrict__ start, const int2* __restrict__ csr,
    float* __restrict__ out) {
  int lane = threadIdx.x & 15;                 // uint2 index, valid < 10
  int node = blockIdx.x * 16 + (threadIdx.x >> 4);
  if (node >= N_NODES || lane >= 10) return;
  const uint2* rows = (const uint2*)xw;        // row stride 10 uint2
  float di = dinv[node];
  float w0 = di * di;
  float4 bb = ((const float4*)bias)[lane];
  float4 sv = bf4(rows[(size_t)node * 10 + lane]);
  float4 acc;
  acc.x = bb.x + w0 * sv.x; acc.y = bb.y + w0 * sv.y;
  acc.z = bb.z + w0 * sv.z; acc.w = bb.w + w0 * sv.w;
  int e0 = start[node], e1 = start[node + 1];
  for (int e = e0; e < e1; ++e) {
    int2 c = csr[e];
    float w = __int_as_float(c.y) * dinv[c.x] * di;
    float4 v = bf4(rows[(size_t)c.x * 10 + lane]);
    acc.x += w * v.x; acc.y += w * v.y; acc.z += w * v.z; acc.w += w * v.w;
  }
  ((float4*)out)[(size_t)node * 10 + lane] = acc;
}

// ---------------- batch norm stats ----------------

__global__ __launch_bounds__(256) void k_bnstats(const float* __restrict__ x,
    float* __restrict__ sums) {
  int f = threadIdx.x & 127;
  int half = threadIdx.x >> 7;
  float s = 0.f, sq = 0.f;
  for (int row = blockIdx.x * 2 + half; row < N_NODES; row += gridDim.x * 2) {
    float v = x[(size_t)row * 128 + f];
    s += v; sq += v * v;
  }
  __shared__ float ls[256], lq[256];
  ls[threadIdx.x] = s; lq[threadIdx.x] = sq;
  __syncthreads();
  if (half == 0) {
    s += ls[threadIdx.x + 128];
    sq += lq[threadIdx.x + 128];
    atomicAdd(&sums[f], s);
    atomicAdd(&sums[128 + f], sq);
  }
}

__global__ void k_bnfinal(const float* __restrict__ sums,
    const float* __restrict__ gamma, const float* __restrict__ beta,
    float* __restrict__ ssb) {
  int f = threadIdx.x;  // 128 threads
  float inv_n = 1.0f / (float)N_NODES;
  float mu = sums[f] * inv_n;
  float var = sums[128 + f] * inv_n - mu * mu;
  if (var < 0.f) var = 0.f;
  float scale = gamma[f] * rsqrtf(var + BN_EPS);
  ssb[f] = scale;
  ssb[128 + f] = beta[f] - mu * scale;
}

// ---------------- log_softmax over 40 classes ----------------

__global__ __launch_bounds__(256) void k_logsm(float* __restrict__ io) {
  int lane = threadIdx.x & 63;
  int node = blockIdx.x * 4 + (threadIdx.x >> 6);
  if (node >= N_NODES) return;
  float v = (lane < 40) ? io[(size_t)node * 40 + lane] : -1e30f;
  float m = v;
  #pragma unroll
  for (int off = 32; off >= 1; off >>= 1) m = fmaxf(m, __shfl_xor(m, off));
  float e = (lane < 40) ? expf(v - m) : 0.f;
  float ssum = e;
  #pragma unroll
  for (int off = 32; off >= 1; off >>= 1) ssum += __shfl_xor(ssum, off);
  if (lane < 40) io[(size_t)node * 40 + lane] = v - m - logf(ssum);
}

// ---------------- launch ----------------

extern "C" void kernel_launch(void* const* d_in, const int* in_sizes, int n_in,
                              void* d_out, int out_size, void* d_ws, size_t ws_size,
                              hipStream_t stream) {
  const float* x   = (const float*)d_in[0];
  const int*   ei  = (const int*)d_in[1];
  const float* ew  = (const float*)d_in[2];
  const float* W1  = (const float*)d_in[3];
  const float* b1  = (const float*)d_in[4];
  const float* g1  = (const float*)d_in[5];
  const float* be1 = (const float*)d_in[6];
  const float* W2  = (const float*)d_in[7];
  const float* b2  = (const float*)d_in[8];
  const float* g2  = (const float*)d_in[9];
  const float* be2 = (const float*)d_in[10];
  const float* W3  = (const float*)d_in[11];
  const float* b3  = (const float*)d_in[12];
  float* out = (float*)d_out;
  int E = in_sizes[2];
  const int* src = ei;
  const int* dst = ei + E;

  char* p = (char*)d_ws;
  auto alloc = [&](size_t bytes) {
    char* r = p; p += (bytes + 255) & ~(size_t)255; return r;
  };
  int*   count = (int*)  alloc((size_t)N_NODES * 4);
  int*   cursor= (int*)  alloc((size_t)N_NODES * 4);
  int*   incl  = (int*)  alloc((size_t)N_NODES * 4);
  int*   bsums = (int*)  alloc(64 * 4);
  int*   startA= (int*)  alloc((size_t)(N_NODES + 1) * 4);
  float* dinv  = (float*)alloc((size_t)N_NODES * 4);
  int2*  csr   = (int2*) alloc((size_t)E * 8);
  float* stats = (float*)alloc(256 * 4);
  float* ssb   = (float*)alloc(256 * 4);
  unsigned short* xw16 = (unsigned short*)alloc((size_t)N_NODES * 128 * 2);
  float* bufB  = (float*)alloc((size_t)N_NODES * 128 * 4);

  int nblkN = (N_NODES + 255) / 256;
  int nblkE = (E + 255) / 256;
  int nb = (N_NODES + 1023) / 1024;

  hipMemsetAsync(count, 0, (size_t)N_NODES * 4, stream);
  hipMemsetAsync(cursor, 0, (size_t)N_NODES * 4, stream);
  k_count<<<nblkE, 256, 0, stream>>>(dst, E, count);
  k_scan_chunk<<<nb, 1024, 0, stream>>>(count, incl, bsums, N_NODES);
  k_scan_tops<<<1, 64, 0, stream>>>(bsums, nb);
  k_scan_fin<<<nblkN, 256, 0, stream>>>(incl, count, bsums, startA, N_NODES);
  k_fill<<<nblkE, 256, 0, stream>>>(src, dst, ew, E, startA, cursor, csr);
  k_degdinv<<<(N_NODES + 15) / 16, 256, 0, stream>>>(csr, startA, dinv);

  dim3 gemmGrid((N_NODES + 63) / 64, 2);
  dim3 gemmGrid3((N_NODES + 63) / 64, 1);

  // layer 1
  k_gemm<<<gemmGrid, 256, 0, stream>>>(x, W1, nullptr, xw16, 128);
  k_agg128b<<<(N_NODES + 7) / 8, 256, 0, stream>>>(xw16, b1, dinv, startA, csr, bufB);
  hipMemsetAsync(stats, 0, 256 * 4, stream);
  k_bnstats<<<256, 256, 0, stream>>>(bufB, stats);
  k_bnfinal<<<1, 128, 0, stream>>>(stats, g1, be1, ssb);

  // layer 2 (BN1+ReLU fused into GEMM staging)
  k_gemm<<<gemmGrid, 256, 0, stream>>>(bufB, W2, ssb, xw16, 128);
  k_agg128b<<<(N_NODES + 7) / 8, 256, 0, stream>>>(xw16, b2, dinv, startA, csr, bufB);
  hipMemsetAsync(stats, 0, 256 * 4, stream);
  k_bnstats<<<256, 256, 0, stream>>>(bufB, stats);
  k_bnfinal<<<1, 128, 0, stream>>>(stats, g2, be2, ssb);

  // layer 3 (BN2+ReLU fused into GEMM staging)
  k_gemm<<<gemmGrid3, 256, 0, stream>>>(bufB, W3, ssb, xw16, 40);
  k_agg40b<<<(N_NODES + 15) / 16, 256, 0, stream>>>(xw16, b3, dinv, startA, csr, out);
  k_logsm<<<(N_NODES + 3) / 4, 256, 0, stream>>>(out);
}

// Round 3
// 378.435 us; speedup vs baseline: 1.3501x; 1.1314x over previous
//
#include <hip/hip_runtime.h>
#include <cstdint>
#include <cstddef>

#define N_NODES 50000
#define BN_EPS 1e-5f

typedef unsigned int uint32;
typedef unsigned short ushort16;

// ---------------- helpers ----------------

__device__ inline unsigned short bf16rn(float f) {
  unsigned int u = __float_as_uint(f);
  u += 0x7fffu + ((u >> 16) & 1u);
  return (unsigned short)(u >> 16);
}
__device__ inline float unbf(uint32 u) {           // low 16 bits -> float
  return __uint_as_float(u << 16);
}
__device__ inline float lo16(uint32 u) { return __uint_as_float(u << 16); }
__device__ inline float hi16(uint32 u) { return __uint_as_float(u & 0xffff0000u); }
__device__ inline uint32 pack2(float a, float b) {
  return (uint32)bf16rn(a) | ((uint32)bf16rn(b) << 16);
}

// ---------------- CSR build (8-way pseudo-XCD replicated counters) ----------------

__global__ __launch_bounds__(256) void k_count8(const int* __restrict__ dst, int E,
                                                int* __restrict__ count8) {
  int e = blockIdx.x * 256 + threadIdx.x;
  if (e < E) atomicAdd(&count8[(blockIdx.x & 7) * N_NODES + dst[e]], 1);
}

__global__ __launch_bounds__(1024) void k_scan_chunk(const int* __restrict__ count8,
    int* __restrict__ incl, int* __restrict__ tot, int* __restrict__ bsums, int n) {
  __shared__ int tmp[1024];
  int gid = blockIdx.x * 1024 + threadIdx.x;
  int v = 0;
  if (gid < n) {
    v = 1;  // self-loop slot
    #pragma unroll
    for (int g = 0; g < 8; ++g) v += count8[g * N_NODES + gid];
    tot[gid] = v;
  }
  tmp[threadIdx.x] = v;
  __syncthreads();
  for (int off = 1; off < 1024; off <<= 1) {
    int a = (threadIdx.x >= off) ? tmp[threadIdx.x - off] : 0;
    __syncthreads();
    tmp[threadIdx.x] += a;
    __syncthreads();
  }
  if (gid < n) incl[gid] = tmp[threadIdx.x];
  if (threadIdx.x == 1023) bsums[blockIdx.x] = tmp[1023];
}

__global__ void k_scan_tops(int* bsums, int nb) {
  if (threadIdx.x == 0 && blockIdx.x == 0) {
    int acc = 0;
    for (int i = 0; i < nb; ++i) { int t = bsums[i]; bsums[i] = acc; acc += t; }
  }
}

// start[], per-replica bases, and the self-loop CSR entry
__global__ __launch_bounds__(256) void k_scan_fin(const int* __restrict__ incl,
    const int* __restrict__ tot, const int* __restrict__ count8,
    const int* __restrict__ bsums, int* __restrict__ start,
    int* __restrict__ base8, uint32* __restrict__ csr, int n) {
  int gid = blockIdx.x * 256 + threadIdx.x;
  if (gid < n) {
    int st = incl[gid] - tot[gid] + bsums[gid >> 10];
    start[gid] = st;
    csr[st] = (0x3F80u << 16) | (uint32)gid;   // self: w=1.0bf16, src=gid
    int running = st + 1;
    #pragma unroll
    for (int g = 0; g < 8; ++g) {
      base8[g * N_NODES + gid] = running;
      running += count8[g * N_NODES + gid];
    }
    if (gid == n - 1) start[n] = incl[gid] + bsums[gid >> 10];
  }
}

__global__ __launch_bounds__(256) void k_fill8(const int* __restrict__ src,
    const int* __restrict__ dst, const float* __restrict__ ew, int E,
    const int* __restrict__ base8, int* __restrict__ cursor8,
    uint32* __restrict__ csr) {
  int e = blockIdx.x * 256 + threadIdx.x;
  if (e < E) {
    int d = dst[e];
    int g = blockIdx.x & 7;
    int p = base8[g * N_NODES + d] + atomicAdd(&cursor8[g * N_NODES + d], 1);
    csr[p] = ((uint32)bf16rn(ew[e]) << 16) | (uint32)src[e];
  }
}

// deg = sum of bucket weights (self 1.0 included); dinv = rsqrt(deg)
__global__ __launch_bounds__(256) void k_degdinv(const uint32* __restrict__ csr,
    const int* __restrict__ start, float* __restrict__ dinv) {
  int lane = threadIdx.x & 15;
  int node = blockIdx.x * 16 + (threadIdx.x >> 4);
  if (node >= N_NODES) return;
  int e0 = start[node], e1 = start[node + 1];
  float s = 0.f;
  for (int e = e0 + lane; e < e1; e += 16) s += unbf(csr[e] >> 16);
  #pragma unroll
  for (int off = 8; off >= 1; off >>= 1) s += __shfl_xor(s, off, 16);
  if (lane == 0) dinv[node] = rsqrtf(s);
}

// rewrite csr weights in place: w <- w * dinv[src] * dinv[node]
__global__ __launch_bounds__(256) void k_wnorm(uint32* __restrict__ csr,
    const int* __restrict__ start, const float* __restrict__ dinv) {
  int lane = threadIdx.x & 15;
  int node = blockIdx.x * 16 + (threadIdx.x >> 4);
  if (node >= N_NODES) return;
  float di = dinv[node];
  int e0 = start[node], e1 = start[node + 1];
  for (int e = e0 + lane; e < e1; e += 16) {
    uint32 c = csr[e];
    int s = c & 0xffff;
    float w = unbf(c >> 16) * dinv[s] * di;
    csr[e] = ((uint32)bf16rn(w) << 16) | (uint32)s;
  }
}

// ---------------- GEMM: out16[N,Fout] = act(X)[N,128] @ W[128,Fout] ----------------
// XT = float (f32 rows) or unsigned short (bf16 rows)
// if ssb != null: act(x)_f = max(0, x_f * ssb[f] + ssb[128+f])

template <typename XT>
__global__ __launch_bounds__(256) void k_gemm(const XT* __restrict__ X,
    const float* __restrict__ W, const float* __restrict__ ssb,
    unsigned short* __restrict__ out16, int Fout) {
  __shared__ float Xs[64][68];
  __shared__ float Ws[64][68];
  int tid = threadIdx.x;
  int r0 = blockIdx.x * 64;
  int c0 = blockIdx.y * 64;
  int ty = tid >> 4, tx = tid & 15;
  float acc[4][4] = {};
  for (int k0 = 0; k0 < 128; k0 += 64) {
    if (sizeof(XT) == 4) {
      #pragma unroll
      for (int j = 0; j < 4; ++j) {
        int f4 = tid + j * 256;
        int row = f4 >> 4;
        int c4 = (f4 & 15) * 4;
        float4 v = make_float4(0.f, 0.f, 0.f, 0.f);
        int gr = r0 + row;
        if (gr < N_NODES)
          v = *reinterpret_cast<const float4*>(
                reinterpret_cast<const float*>(X) + (size_t)gr * 128 + k0 + c4);
        if (ssb) {
          float4 sc = reinterpret_cast<const float4*>(ssb)[(k0 + c4) >> 2];
          float4 sh = reinterpret_cast<const float4*>(ssb + 128)[(k0 + c4) >> 2];
          v.x = fmaxf(0.f, v.x * sc.x + sh.x);
          v.y = fmaxf(0.f, v.y * sc.y + sh.y);
          v.z = fmaxf(0.f, v.z * sc.z + sh.z);
          v.w = fmaxf(0.f, v.w * sc.w + sh.w);
        }
        *reinterpret_cast<float4*>(&Xs[row][c4]) = v;
      }
    } else {
      #pragma unroll
      for (int j = 0; j < 2; ++j) {
        int f8 = tid + j * 256;            // 0..511
        int row = f8 >> 3;                 // 0..63
        int c8 = (f8 & 7) * 8;             // 0..56
        int gr = r0 + row;
        uint4 v = make_uint4(0, 0, 0, 0);
        if (gr < N_NODES)
          v = *reinterpret_cast<const uint4*>(
                reinterpret_cast<const unsigned short*>(X) + (size_t)gr * 128 + k0 + c8);
        float f[8] = { lo16(v.x), hi16(v.x), lo16(v.y), hi16(v.y),
                       lo16(v.z), hi16(v.z), lo16(v.w), hi16(v.w) };
        if (ssb) {
          #pragma unroll
          for (int i = 0; i < 8; ++i)
            f[i] = fmaxf(0.f, f[i] * ssb[k0 + c8 + i] + ssb[128 + k0 + c8 + i]);
        }
        #pragma unroll
        for (int i = 0; i < 8; ++i) Xs[row][c8 + i] = f[i];
      }
    }
    #pragma unroll
    for (int j = 0; j < 4; ++j) {
      int f4 = tid + j * 256;
      int k = f4 >> 4;
      int c4 = (f4 & 15) * 4;
      int gc = c0 + c4;
      float4 v = make_float4(0.f, 0.f, 0.f, 0.f);
      if (gc + 3 < Fout)
        v = *reinterpret_cast<const float4*>(&W[(size_t)(k0 + k) * Fout + gc]);
      *reinterpret_cast<float4*>(&Ws[k][c4]) = v;
    }
    __syncthreads();
    #pragma unroll 16
    for (int k = 0; k < 64; ++k) {
      float4 wv = *reinterpret_cast<const float4*>(&Ws[k][tx * 4]);
      float xv0 = Xs[ty * 4 + 0][k];
      float xv1 = Xs[ty * 4 + 1][k];
      float xv2 = Xs[ty * 4 + 2][k];
      float xv3 = Xs[ty * 4 + 3][k];
      acc[0][0] += xv0 * wv.x; acc[0][1] += xv0 * wv.y; acc[0][2] += xv0 * wv.z; acc[0][3] += xv0 * wv.w;
      acc[1][0] += xv1 * wv.x; acc[1][1] += xv1 * wv.y; acc[1][2] += xv1 * wv.z; acc[1][3] += xv1 * wv.w;
      acc[2][0] += xv2 * wv.x; acc[2][1] += xv2 * wv.y; acc[2][2] += xv2 * wv.z; acc[2][3] += xv2 * wv.w;
      acc[3][0] += xv3 * wv.x; acc[3][1] += xv3 * wv.y; acc[3][2] += xv3 * wv.z; acc[3][3] += xv3 * wv.w;
    }
    __syncthreads();
  }
  #pragma unroll
  for (int i = 0; i < 4; ++i) {
    int gr = r0 + ty * 4 + i;
    if (gr >= N_NODES) continue;
    int gc = c0 + tx * 4;
    if (gc + 3 < Fout) {
      ushort4 o;
      o.x = bf16rn(acc[i][0]);
      o.y = bf16rn(acc[i][1]);
      o.z = bf16rn(acc[i][2]);
      o.w = bf16rn(acc[i][3]);
      *reinterpret_cast<ushort4*>(&out16[(size_t)gr * Fout + gc]) = o;
    }
  }
}

// ---------------- aggregation: 1 wave per node, 4 edges in flight ----------------

__global__ __launch_bounds__(256) void k_agg128c(const unsigned short* __restrict__ xw,
    const float* __restrict__ bias, const int* __restrict__ start,
    const uint32* __restrict__ csr, unsigned short* __restrict__ out16) {
  int lane = threadIdx.x & 63;
  int node = blockIdx.x * 4 + (threadIdx.x >> 6);
  if (node >= N_NODES) return;
  int sub = lane >> 4;       // 0..3: which edge of the 4-in-flight
  int fl  = lane & 15;       // feature group: features [fl*8, fl*8+8)
  const uint4* rows = (const uint4*)xw;   // 16 uint4 per row
  float acc[8] = {};
  int e0 = start[node], e1 = start[node + 1];
  for (int e = e0 + sub; e < e1; e += 4) {
    uint32 c = csr[e];
    float w = unbf(c >> 16);
    int s = c & 0xffff;
    uint4 v = rows[(size_t)s * 16 + fl];
    acc[0] += w * lo16(v.x); acc[1] += w * hi16(v.x);
    acc[2] += w * lo16(v.y); acc[3] += w * hi16(v.y);
    acc[4] += w * lo16(v.z); acc[5] += w * hi16(v.z);
    acc[6] += w * lo16(v.w); acc[7] += w * hi16(v.w);
  }
  #pragma unroll
  for (int k = 0; k < 8; ++k) acc[k] += __shfl_xor(acc[k], 16);
  #pragma unroll
  for (int k = 0; k < 8; ++k) acc[k] += __shfl_xor(acc[k], 32);
  if (sub == 0) {
    float4 b0 = ((const float4*)bias)[fl * 2];
    float4 b1 = ((const float4*)bias)[fl * 2 + 1];
    acc[0] += b0.x; acc[1] += b0.y; acc[2] += b0.z; acc[3] += b0.w;
    acc[4] += b1.x; acc[5] += b1.y; acc[6] += b1.z; acc[7] += b1.w;
    uint4 o;
    o.x = pack2(acc[0], acc[1]);
    o.y = pack2(acc[2], acc[3]);
    o.z = pack2(acc[4], acc[5]);
    o.w = pack2(acc[6], acc[7]);
    ((uint4*)out16)[(size_t)node * 16 + fl] = o;
  }
}

__global__ __launch_bounds__(256) void k_agg40c(const unsigned short* __restrict__ xw,
    const float* __restrict__ bias, const int* __restrict__ start,
    const uint32* __restrict__ csr, float* __restrict__ out) {
  int lane = threadIdx.x & 63;
  int node = blockIdx.x * 4 + (threadIdx.x >> 6);
  if (node >= N_NODES) return;
  int sub = lane >> 4;
  int fl  = lane & 15;       // valid feature groups: fl < 10 (4 features each)
  bool active = fl < 10;
  int flc = active ? fl : 0;
  const uint2* rows = (const uint2*)xw;   // 10 uint2 per row
  float acc[4] = {};
  int e0 = start[node], e1 = start[node + 1];
  for (int e = e0 + sub; e < e1; e += 4) {
    uint32 c = csr[e];
    float w = unbf(c >> 16);
    int s = c & 0xffff;
    uint2 v = rows[(size_t)s * 10 + flc];
    if (active) {
      acc[0] += w * lo16(v.x); acc[1] += w * hi16(v.x);
      acc[2] += w * lo16(v.y); acc[3] += w * hi16(v.y);
    }
  }
  #pragma unroll
  for (int k = 0; k < 4; ++k) acc[k] += __shfl_xor(acc[k], 16);
  #pragma unroll
  for (int k = 0; k < 4; ++k) acc[k] += __shfl_xor(acc[k], 32);
  if (sub == 0 && active) {
    float4 b = ((const float4*)bias)[fl];
    float4 o = make_float4(acc[0] + b.x, acc[1] + b.y, acc[2] + b.z, acc[3] + b.w);
    *reinterpret_cast<float4*>(&out[(size_t)node * 40 + fl * 4]) = o;
  }
}

// ---------------- batch norm stats (bf16 input) ----------------

__global__ __launch_bounds__(256) void k_bnstats16(const unsigned short* __restrict__ x,
    float* __restrict__ sums) {
  int f = threadIdx.x & 127;
  int half = threadIdx.x >> 7;
  float s = 0.f, sq = 0.f;
  for (int row = blockIdx.x * 2 + half; row < N_NODES; row += gridDim.x * 2) {
    float v = __uint_as_float(((uint32)x[(size_t)row * 128 + f]) << 16);
    s += v; sq += v * v;
  }
  __shared__ float ls[256], lq[256];
  ls[threadIdx.x] = s; lq[threadIdx.x] = sq;
  __syncthreads();
  if (half == 0) {
    s += ls[threadIdx.x + 128];
    sq += lq[threadIdx.x + 128];
    atomicAdd(&sums[f], s);
    atomicAdd(&sums[128 + f], sq);
  }
}

__global__ void k_bnfinal(const float* __restrict__ sums,
    const float* __restrict__ gamma, const float* __restrict__ beta,
    float* __restrict__ ssb) {
  int f = threadIdx.x;  // 128 threads
  float inv_n = 1.0f / (float)N_NODES;
  float mu = sums[f] * inv_n;
  float var = sums[128 + f] * inv_n - mu * mu;
  if (var < 0.f) var = 0.f;
  float scale = gamma[f] * rsqrtf(var + BN_EPS);
  ssb[f] = scale;
  ssb[128 + f] = beta[f] - mu * scale;
}

// ---------------- log_softmax over 40 classes ----------------

__global__ __launch_bounds__(256) void k_logsm(float* __restrict__ io) {
  int lane = threadIdx.x & 63;
  int node = blockIdx.x * 4 + (threadIdx.x >> 6);
  if (node >= N_NODES) return;
  float v = (lane < 40) ? io[(size_t)node * 40 + lane] : -1e30f;
  float m = v;
  #pragma unroll
  for (int off = 32; off >= 1; off >>= 1) m = fmaxf(m, __shfl_xor(m, off));
  float e = (lane < 40) ? expf(v - m) : 0.f;
  float ssum = e;
  #pragma unroll
  for (int off = 32; off >= 1; off >>= 1) ssum += __shfl_xor(ssum, off);
  if (lane < 40) io[(size_t)node * 40 + lane] = v - m - logf(ssum);
}

// ---------------- launch ----------------

extern "C" void kernel_launch(void* const* d_in, const int* in_sizes, int n_in,
                              void* d_out, int out_size, void* d_ws, size_t ws_size,
                              hipStream_t stream) {
  const float* x   = (const float*)d_in[0];
  const int*   ei  = (const int*)d_in[1];
  const float* ew  = (const float*)d_in[2];
  const float* W1  = (const float*)d_in[3];
  const float* b1  = (const float*)d_in[4];
  const float* g1  = (const float*)d_in[5];
  const float* be1 = (const float*)d_in[6];
  const float* W2  = (const float*)d_in[7];
  const float* b2  = (const float*)d_in[8];
  const float* g2  = (const float*)d_in[9];
  const float* be2 = (const float*)d_in[10];
  const float* W3  = (const float*)d_in[11];
  const float* b3  = (const float*)d_in[12];
  float* out = (float*)d_out;
  int E = in_sizes[2];
  const int* src = ei;
  const int* dst = ei + E;

  char* p = (char*)d_ws;
  auto alloc = [&](size_t bytes) {
    char* r = p; p += (bytes + 255) & ~(size_t)255; return r;
  };
  int*    count8 = (int*)   alloc((size_t)8 * N_NODES * 4);
  int*    cursor8= (int*)   alloc((size_t)8 * N_NODES * 4);
  int*    base8  = (int*)   alloc((size_t)8 * N_NODES * 4);
  int*    incl   = (int*)   alloc((size_t)N_NODES * 4);
  int*    tot    = (int*)   alloc((size_t)N_NODES * 4);
  int*    bsums  = (int*)   alloc(64 * 4);
  int*    startA = (int*)   alloc((size_t)(N_NODES + 1) * 4);
  float*  dinv   = (float*) alloc((size_t)N_NODES * 4);
  uint32* csr    = (uint32*)alloc((size_t)(E + N_NODES) * 4);
  float*  stats  = (float*) alloc(256 * 4);
  float*  ssb    = (float*) alloc(256 * 4);
  unsigned short* xw16  = (unsigned short*)alloc((size_t)N_NODES * 128 * 2);
  unsigned short* buf16 = (unsigned short*)alloc((size_t)N_NODES * 128 * 2);

  int nblkN = (N_NODES + 255) / 256;
  int nblkE = (E + 255) / 256;
  int nb = (N_NODES + 1023) / 1024;

  hipMemsetAsync(count8, 0, (size_t)8 * N_NODES * 4, stream);
  hipMemsetAsync(cursor8, 0, (size_t)8 * N_NODES * 4, stream);
  k_count8<<<nblkE, 256, 0, stream>>>(dst, E, count8);
  k_scan_chunk<<<nb, 1024, 0, stream>>>(count8, incl, tot, bsums, N_NODES);
  k_scan_tops<<<1, 64, 0, stream>>>(bsums, nb);
  k_scan_fin<<<nblkN, 256, 0, stream>>>(incl, tot, count8, bsums, startA, base8, csr, N_NODES);
  k_fill8<<<nblkE, 256, 0, stream>>>(src, dst, ew, E, base8, cursor8, csr);
  k_degdinv<<<(N_NODES + 15) / 16, 256, 0, stream>>>(csr, startA, dinv);
  k_wnorm<<<(N_NODES + 15) / 16, 256, 0, stream>>>(csr, startA, dinv);

  dim3 gemmGrid((N_NODES + 63) / 64, 2);
  dim3 gemmGrid3((N_NODES + 63) / 64, 1);
  int aggGrid = (N_NODES + 3) / 4;

  // layer 1
  k_gemm<float><<<gemmGrid, 256, 0, stream>>>(x, W1, nullptr, xw16, 128);
  k_agg128c<<<aggGrid, 256, 0, stream>>>(xw16, b1, startA, csr, buf16);
  hipMemsetAsync(stats, 0, 256 * 4, stream);
  k_bnstats16<<<256, 256, 0, stream>>>(buf16, stats);
  k_bnfinal<<<1, 128, 0, stream>>>(stats, g1, be1, ssb);

  // layer 2 (BN1+ReLU fused into GEMM staging)
  k_gemm<unsigned short><<<gemmGrid, 256, 0, stream>>>(buf16, W2, ssb, xw16, 128);
  k_agg128c<<<aggGrid, 256, 0, stream>>>(xw16, b2, startA, csr, buf16);
  hipMemsetAsync(stats, 0, 256 * 4, stream);
  k_bnstats16<<<256, 256, 0, stream>>>(buf16, stats);
  k_bnfinal<<<1, 128, 0, stream>>>(stats, g2, be2, ssb);

  // layer 3 (BN2+ReLU fused into GEMM staging)
  k_gemm<unsigned short><<<gemmGrid3, 256, 0, stream>>>(buf16, W3, ssb, xw16, 40);
  k_agg40c<<<aggGrid, 256, 0, stream>>>(xw16, b3, startA, csr, out);
  k_logsm<<<aggGrid, 256, 0, stream>>>(out);
}

// Round 4
// 348.462 us; speedup vs baseline: 1.4662x; 1.0860x over previous
//
#include <hip/hip_runtime.h>
#include <cstdint>
#include <cstddef>

#define N_NODES 50000
#define BN_EPS 1e-5f
#define NPB 256                       // nodes per bucket
#define NB ((N_NODES + NPB - 1) / NPB)  // 196 buckets
#define EPB_A 8192                    // edges per phase-A block

typedef unsigned int uint32;

// ---------------- helpers ----------------

__device__ inline unsigned short bf16rn(float f) {
  unsigned int u = __float_as_uint(f);
  u += 0x7fffu + ((u >> 16) & 1u);
  return (unsigned short)(u >> 16);
}
__device__ inline float unbf(uint32 u) { return __uint_as_float(u << 16); }
__device__ inline float lo16(uint32 u) { return __uint_as_float(u << 16); }
__device__ inline float hi16(uint32 u) { return __uint_as_float(u & 0xffff0000u); }
__device__ inline uint32 pack2(float a, float b) {
  return (uint32)bf16rn(a) | ((uint32)bf16rn(b) << 16);
}

// ---------------- CSR build: binned two-phase ----------------

// exact per-bucket edge histogram
__global__ __launch_bounds__(256) void k_ehist(const int* __restrict__ dst, int E,
                                               int* __restrict__ histB) {
  __shared__ int h[NB];
  for (int i = threadIdx.x; i < NB; i += 256) h[i] = 0;
  __syncthreads();
  int base = blockIdx.x * EPB_A;
  for (int i = threadIdx.x; i < EPB_A; i += 256) {
    int e = base + i;
    if (e < E) atomicAdd(&h[dst[e] >> 8], 1);
  }
  __syncthreads();
  for (int i = threadIdx.x; i < NB; i += 256)
    if (h[i]) atomicAdd(&histB[i], h[i]);
}

// serial prefix over NB buckets: rbase (records), cbase (csr)
__global__ void k_prefix(const int* __restrict__ histB, int E,
                         int* __restrict__ rbase, int* __restrict__ cbase,
                         int* __restrict__ start) {
  if (threadIdx.x == 0 && blockIdx.x == 0) {
    int r = 0, c = 0;
    for (int b = 0; b < NB; ++b) {
      int npb = (b == NB - 1) ? (N_NODES - b * NPB) : NPB;
      rbase[b] = r; cbase[b] = c;
      r += histB[b]; c += histB[b] + npb;
    }
    rbase[NB] = r;
    start[N_NODES] = c;   // == E + N_NODES
  }
}

// phase A: bin edges into per-bucket record regions, run-coalesced writes
__global__ __launch_bounds__(256) void k_binA(const int* __restrict__ src,
    const int* __restrict__ dst, const float* __restrict__ ew, int E,
    const int* __restrict__ rbase, int* __restrict__ gcur,
    uint2* __restrict__ bins) {
  __shared__ int h[NB], gb[NB], cur[NB];
  for (int i = threadIdx.x; i < NB; i += 256) h[i] = 0;
  __syncthreads();
  int base = blockIdx.x * EPB_A;
  for (int i = threadIdx.x; i < EPB_A; i += 256) {
    int e = base + i;
    if (e < E) atomicAdd(&h[dst[e] >> 8], 1);
  }
  __syncthreads();
  for (int i = threadIdx.x; i < NB; i += 256) {
    cur[i] = 0;
    gb[i] = h[i] ? (rbase[i] + atomicAdd(&gcur[i], h[i])) : 0;
  }
  __syncthreads();
  for (int i = threadIdx.x; i < EPB_A; i += 256) {
    int e = base + i;
    if (e < E) {
      int d = dst[e];
      int g = d >> 8;
      int p = gb[g] + atomicAdd(&cur[g], 1);
      bins[p] = make_uint2((uint32)src[e] | ((uint32)(d & 255) << 16),
                           __float_as_uint(ew[e]));
    }
  }
}

// phase B: one block per bucket: local hist+scan, write start/dinv/self, scatter csr
__global__ __launch_bounds__(256) void k_binB(const uint2* __restrict__ bins,
    const int* __restrict__ rbase, const int* __restrict__ cbase,
    int* __restrict__ start, float* __restrict__ dinv, uint32* __restrict__ csr) {
  __shared__ int h[256], cur[256], ofs[256], sc[256];
  __shared__ float deg[256];
  int tid = threadIdx.x;
  int b = blockIdx.x;
  int node0 = b << 8;
  int npb = min(NPB, N_NODES - node0);
  h[tid] = 0; deg[tid] = 1.0f;   // self-loop weight
  __syncthreads();
  int r0 = rbase[b], r1 = rbase[b + 1];
  for (int i = r0 + tid; i < r1; i += 256) {
    uint2 rec = bins[i];
    int dl = (rec.x >> 16) & 255;
    atomicAdd(&h[dl], 1);
    atomicAdd(&deg[dl], __uint_as_float(rec.y));
  }
  __syncthreads();
  int v = (tid < npb) ? 1 + h[tid] : 0;
  sc[tid] = v;
  __syncthreads();
  for (int off = 1; off < 256; off <<= 1) {
    int a = (tid >= off) ? sc[tid - off] : 0;
    __syncthreads();
    sc[tid] += a;
    __syncthreads();
  }
  int cb = cbase[b];
  if (tid < npb) {
    int segBase = cb + sc[tid] - v;      // exclusive prefix
    int node = node0 + tid;
    start[node] = segBase;
    csr[segBase] = (0x3F80u << 16) | (uint32)node;   // self: w=1.0
    dinv[node] = rsqrtf(deg[tid]);
    ofs[tid] = segBase + 1;
    cur[tid] = 0;
  }
  __syncthreads();
  for (int i = r0 + tid; i < r1; i += 256) {
    uint2 rec = bins[i];
    int dl = (rec.x >> 16) & 255;
    int p = ofs[dl] + atomicAdd(&cur[dl], 1);
    csr[p] = ((uint32)bf16rn(__uint_as_float(rec.y)) << 16) | (rec.x & 0xffff);
  }
}

// rewrite csr weights in place: w <- w * dinv[src] * dinv[node]
__global__ __launch_bounds__(256) void k_wnorm(uint32* __restrict__ csr,
    const int* __restrict__ start, const float* __restrict__ dinv) {
  int lane = threadIdx.x & 15;
  int node = blockIdx.x * 16 + (threadIdx.x >> 4);
  if (node >= N_NODES) return;
  float di = dinv[node];
  int e0 = start[node], e1 = start[node + 1];
  for (int e = e0 + lane; e < e1; e += 16) {
    uint32 c = csr[e];
    int s = c & 0xffff;
    float w = unbf(c >> 16) * dinv[s] * di;
    csr[e] = ((uint32)bf16rn(w) << 16) | (uint32)s;
  }
}

// ---------------- GEMM: out16[N,Fout] = act(X)[N,128] @ W[128,Fout] ----------------

template <typename XT>
__global__ __launch_bounds__(256) void k_gemm(const XT* __restrict__ X,
    const float* __restrict__ W, const float* __restrict__ ssb,
    unsigned short* __restrict__ out16, int Fout) {
  __shared__ float Xs[64][68];
  __shared__ float Ws[64][68];
  int tid = threadIdx.x;
  int r0 = blockIdx.x * 64;
  int c0 = blockIdx.y * 64;
  int ty = tid >> 4, tx = tid & 15;
  float acc[4][4] = {};
  for (int k0 = 0; k0 < 128; k0 += 64) {
    if (sizeof(XT) == 4) {
      #pragma unroll
      for (int j = 0; j < 4; ++j) {
        int f4 = tid + j * 256;
        int row = f4 >> 4;
        int c4 = (f4 & 15) * 4;
        float4 v = make_float4(0.f, 0.f, 0.f, 0.f);
        int gr = r0 + row;
        if (gr < N_NODES)
          v = *reinterpret_cast<const float4*>(
                reinterpret_cast<const float*>(X) + (size_t)gr * 128 + k0 + c4);
        if (ssb) {
          float4 sc = reinterpret_cast<const float4*>(ssb)[(k0 + c4) >> 2];
          float4 sh = reinterpret_cast<const float4*>(ssb + 128)[(k0 + c4) >> 2];
          v.x = fmaxf(0.f, v.x * sc.x + sh.x);
          v.y = fmaxf(0.f, v.y * sc.y + sh.y);
          v.z = fmaxf(0.f, v.z * sc.z + sh.z);
          v.w = fmaxf(0.f, v.w * sc.w + sh.w);
        }
        *reinterpret_cast<float4*>(&Xs[row][c4]) = v;
      }
    } else {
      #pragma unroll
      for (int j = 0; j < 2; ++j) {
        int f8 = tid + j * 256;
        int row = f8 >> 3;
        int c8 = (f8 & 7) * 8;
        int gr = r0 + row;
        uint4 v = make_uint4(0, 0, 0, 0);
        if (gr < N_NODES)
          v = *reinterpret_cast<const uint4*>(
                reinterpret_cast<const unsigned short*>(X) + (size_t)gr * 128 + k0 + c8);
        float f[8] = { lo16(v.x), hi16(v.x), lo16(v.y), hi16(v.y),
                       lo16(v.z), hi16(v.z), lo16(v.w), hi16(v.w) };
        if (ssb) {
          #pragma unroll
          for (int i = 0; i < 8; ++i)
            f[i] = fmaxf(0.f, f[i] * ssb[k0 + c8 + i] + ssb[128 + k0 + c8 + i]);
        }
        #pragma unroll
        for (int i = 0; i < 8; ++i) Xs[row][c8 + i] = f[i];
      }
    }
    #pragma unroll
    for (int j = 0; j < 4; ++j) {
      int f4 = tid + j * 256;
      int k = f4 >> 4;
      int c4 = (f4 & 15) * 4;
      int gc = c0 + c4;
      float4 v = make_float4(0.f, 0.f, 0.f, 0.f);
      if (gc + 3 < Fout)
        v = *reinterpret_cast<const float4*>(&W[(size_t)(k0 + k) * Fout + gc]);
      *reinterpret_cast<float4*>(&Ws[k][c4]) = v;
    }
    __syncthreads();
    #pragma unroll 16
    for (int k = 0; k < 64; ++k) {
      float4 wv = *reinterpret_cast<const float4*>(&Ws[k][tx * 4]);
      float xv0 = Xs[ty * 4 + 0][k];
      float xv1 = Xs[ty * 4 + 1][k];
      float xv2 = Xs[ty * 4 + 2][k];
      float xv3 = Xs[ty * 4 + 3][k];
      acc[0][0] += xv0 * wv.x; acc[0][1] += xv0 * wv.y; acc[0][2] += xv0 * wv.z; acc[0][3] += xv0 * wv.w;
      acc[1][0] += xv1 * wv.x; acc[1][1] += xv1 * wv.y; acc[1][2] += xv1 * wv.z; acc[1][3] += xv1 * wv.w;
      acc[2][0] += xv2 * wv.x; acc[2][1] += xv2 * wv.y; acc[2][2] += xv2 * wv.z; acc[2][3] += xv2 * wv.w;
      acc[3][0] += xv3 * wv.x; acc[3][1] += xv3 * wv.y; acc[3][2] += xv3 * wv.z; acc[3][3] += xv3 * wv.w;
    }
    __syncthreads();
  }
  #pragma unroll
  for (int i = 0; i < 4; ++i) {
    int gr = r0 + ty * 4 + i;
    if (gr >= N_NODES) continue;
    int gc = c0 + tx * 4;
    if (gc + 3 < Fout) {
      ushort4 o;
      o.x = bf16rn(acc[i][0]);
      o.y = bf16rn(acc[i][1]);
      o.z = bf16rn(acc[i][2]);
      o.w = bf16rn(acc[i][3]);
      *reinterpret_cast<ushort4*>(&out16[(size_t)gr * Fout + gc]) = o;
    }
  }
}

// ---------------- aggregation: 1 wave per node, 4 edges in flight ----------------

__global__ __launch_bounds__(256) void k_agg128c(const unsigned short* __restrict__ xw,
    const float* __restrict__ bias, const int* __restrict__ start,
    const uint32* __restrict__ csr, unsigned short* __restrict__ out16) {
  int lane = threadIdx.x & 63;
  int node = blockIdx.x * 4 + (threadIdx.x >> 6);
  if (node >= N_NODES) return;
  int sub = lane >> 4;
  int fl  = lane & 15;
  const uint4* rows = (const uint4*)xw;
  float acc[8] = {};
  int e0 = start[node], e1 = start[node + 1];
  for (int e = e0 + sub; e < e1; e += 4) {
    uint32 c = csr[e];
    float w = unbf(c >> 16);
    int s = c & 0xffff;
    uint4 v = rows[(size_t)s * 16 + fl];
    acc[0] += w * lo16(v.x); acc[1] += w * hi16(v.x);
    acc[2] += w * lo16(v.y); acc[3] += w * hi16(v.y);
    acc[4] += w * lo16(v.z); acc[5] += w * hi16(v.z);
    acc[6] += w * lo16(v.w); acc[7] += w * hi16(v.w);
  }
  #pragma unroll
  for (int k = 0; k < 8; ++k) acc[k] += __shfl_xor(acc[k], 16);
  #pragma unroll
  for (int k = 0; k < 8; ++k) acc[k] += __shfl_xor(acc[k], 32);
  if (sub == 0) {
    float4 b0 = ((const float4*)bias)[fl * 2];
    float4 b1 = ((const float4*)bias)[fl * 2 + 1];
    acc[0] += b0.x; acc[1] += b0.y; acc[2] += b0.z; acc[3] += b0.w;
    acc[4] += b1.x; acc[5] += b1.y; acc[6] += b1.z; acc[7] += b1.w;
    uint4 o;
    o.x = pack2(acc[0], acc[1]);
    o.y = pack2(acc[2], acc[3]);
    o.z = pack2(acc[4], acc[5]);
    o.w = pack2(acc[6], acc[7]);
    ((uint4*)out16)[(size_t)node * 16 + fl] = o;
  }
}

__global__ __launch_bounds__(256) void k_agg40c(const unsigned short* __restrict__ xw,
    const float* __restrict__ bias, const int* __restrict__ start,
    const uint32* __restrict__ csr, float* __restrict__ out) {
  int lane = threadIdx.x & 63;
  int node = blockIdx.x * 4 + (threadIdx.x >> 6);
  if (node >= N_NODES) return;
  int sub = lane >> 4;
  int fl  = lane & 15;
  bool active = fl < 10;
  int flc = active ? fl : 0;
  const uint2* rows = (const uint2*)xw;
  float acc[4] = {};
  int e0 = start[node], e1 = start[node + 1];
  for (int e = e0 + sub; e < e1; e += 4) {
    uint32 c = csr[e];
    float w = unbf(c >> 16);
    int s = c & 0xffff;
    uint2 v = rows[(size_t)s * 10 + flc];
    if (active) {
      acc[0] += w * lo16(v.x); acc[1] += w * hi16(v.x);
      acc[2] += w * lo16(v.y); acc[3] += w * hi16(v.y);
    }
  }
  #pragma unroll
  for (int k = 0; k < 4; ++k) acc[k] += __shfl_xor(acc[k], 16);
  #pragma unroll
  for (int k = 0; k < 4; ++k) acc[k] += __shfl_xor(acc[k], 32);
  if (sub == 0 && active) {
    float4 b = ((const float4*)bias)[fl];
    float4 o = make_float4(acc[0] + b.x, acc[1] + b.y, acc[2] + b.z, acc[3] + b.w);
    *reinterpret_cast<float4*>(&out[(size_t)node * 40 + fl * 4]) = o;
  }
}

// ---------------- batch norm stats (bf16 input) ----------------

__global__ __launch_bounds__(256) void k_bnstats16(const unsigned short* __restrict__ x,
    float* __restrict__ sums) {
  int f = threadIdx.x & 127;
  int half = threadIdx.x >> 7;
  float s = 0.f, sq = 0.f;
  for (int row = blockIdx.x * 2 + half; row < N_NODES; row += gridDim.x * 2) {
    float v = __uint_as_float(((uint32)x[(size_t)row * 128 + f]) << 16);
    s += v; sq += v * v;
  }
  __shared__ float ls[256], lq[256];
  ls[threadIdx.x] = s; lq[threadIdx.x] = sq;
  __syncthreads();
  if (half == 0) {
    s += ls[threadIdx.x + 128];
    sq += lq[threadIdx.x + 128];
    atomicAdd(&sums[f], s);
    atomicAdd(&sums[128 + f], sq);
  }
}

__global__ void k_bnfinal(const float* __restrict__ sums,
    const float* __restrict__ gamma, const float* __restrict__ beta,
    float* __restrict__ ssb) {
  int f = threadIdx.x;
  float inv_n = 1.0f / (float)N_NODES;
  float mu = sums[f] * inv_n;
  float var = sums[128 + f] * inv_n - mu * mu;
  if (var < 0.f) var = 0.f;
  float scale = gamma[f] * rsqrtf(var + BN_EPS);
  ssb[f] = scale;
  ssb[128 + f] = beta[f] - mu * scale;
}

// ---------------- log_softmax over 40 classes ----------------

__global__ __launch_bounds__(256) void k_logsm(float* __restrict__ io) {
  int lane = threadIdx.x & 63;
  int node = blockIdx.x * 4 + (threadIdx.x >> 6);
  if (node >= N_NODES) return;
  float v = (lane < 40) ? io[(size_t)node * 40 + lane] : -1e30f;
  float m = v;
  #pragma unroll
  for (int off = 32; off >= 1; off >>= 1) m = fmaxf(m, __shfl_xor(m, off));
  float e = (lane < 40) ? expf(v - m) : 0.f;
  float ssum = e;
  #pragma unroll
  for (int off = 32; off >= 1; off >>= 1) ssum += __shfl_xor(ssum, off);
  if (lane < 40) io[(size_t)node * 40 + lane] = v - m - logf(ssum);
}

// ---------------- launch ----------------

extern "C" void kernel_launch(void* const* d_in, const int* in_sizes, int n_in,
                              void* d_out, int out_size, void* d_ws, size_t ws_size,
                              hipStream_t stream) {
  const float* x   = (const float*)d_in[0];
  const int*   ei  = (const int*)d_in[1];
  const float* ew  = (const float*)d_in[2];
  const float* W1  = (const float*)d_in[3];
  const float* b1  = (const float*)d_in[4];
  const float* g1  = (const float*)d_in[5];
  const float* be1 = (const float*)d_in[6];
  const float* W2  = (const float*)d_in[7];
  const float* b2  = (const float*)d_in[8];
  const float* g2  = (const float*)d_in[9];
  const float* be2 = (const float*)d_in[10];
  const float* W3  = (const float*)d_in[11];
  const float* b3  = (const float*)d_in[12];
  float* out = (float*)d_out;
  int E = in_sizes[2];
  const int* src = ei;
  const int* dst = ei + E;

  char* p = (char*)d_ws;
  auto alloc = [&](size_t bytes) {
    char* r = p; p += (bytes + 255) & ~(size_t)255; return r;
  };
  int*    histB  = (int*)   alloc((size_t)(NB + 1) * 4);
  int*    rbase  = (int*)   alloc((size_t)(NB + 1) * 4);
  int*    cbase  = (int*)   alloc((size_t)NB * 4);
  int*    gcur   = (int*)   alloc((size_t)NB * 4);
  int*    startA = (int*)   alloc((size_t)(N_NODES + 1) * 4);
  float*  dinv   = (float*) alloc((size_t)N_NODES * 4);
  uint2*  bins   = (uint2*) alloc((size_t)E * 8);
  uint32* csr    = (uint32*)alloc((size_t)(E + N_NODES) * 4);
  float*  stats  = (float*) alloc(256 * 4);
  float*  ssb    = (float*) alloc(256 * 4);
  unsigned short* xw16  = (unsigned short*)alloc((size_t)N_NODES * 128 * 2);
  unsigned short* buf16 = (unsigned short*)alloc((size_t)N_NODES * 128 * 2);

  int nblkA = (E + EPB_A - 1) / EPB_A;

  hipMemsetAsync(histB, 0, (size_t)(NB + 1) * 4, stream);
  hipMemsetAsync(gcur, 0, (size_t)NB * 4, stream);
  k_ehist<<<nblkA, 256, 0, stream>>>(dst, E, histB);
  k_prefix<<<1, 64, 0, stream>>>(histB, E, rbase, cbase, startA);
  k_binA<<<nblkA, 256, 0, stream>>>(src, dst, ew, E, rbase, gcur, bins);
  k_binB<<<NB, 256, 0, stream>>>(bins, rbase, cbase, startA, dinv, csr);
  k_wnorm<<<(N_NODES + 15) / 16, 256, 0, stream>>>(csr, startA, dinv);

  dim3 gemmGrid((N_NODES + 63) / 64, 2);
  dim3 gemmGrid3((N_NODES + 63) / 64, 1);
  int aggGrid = (N_NODES + 3) / 4;

  // layer 1
  k_gemm<float><<<gemmGrid, 256, 0, stream>>>(x, W1, nullptr, xw16, 128);
  k_agg128c<<<aggGrid, 256, 0, stream>>>(xw16, b1, startA, csr, buf16);
  hipMemsetAsync(stats, 0, 256 * 4, stream);
  k_bnstats16<<<256, 256, 0, stream>>>(buf16, stats);
  k_bnfinal<<<1, 128, 0, stream>>>(stats, g1, be1, ssb);

  // layer 2 (BN1+ReLU fused into GEMM staging)
  k_gemm<unsigned short><<<gemmGrid, 256, 0, stream>>>(buf16, W2, ssb, xw16, 128);
  k_agg128c<<<aggGrid, 256, 0, stream>>>(xw16, b2, startA, csr, buf16);
  hipMemsetAsync(stats, 0, 256 * 4, stream);
  k_bnstats16<<<256, 256, 0, stream>>>(buf16, stats);
  k_bnfinal<<<1, 128, 0, stream>>>(stats, g2, be2, ssb);

  // layer 3 (BN2+ReLU fused into GEMM staging)
  k_gemm<unsigned short><<<gemmGrid3, 256, 0, stream>>>(buf16, W3, ssb, xw16, 40);
  k_agg40c<<<aggGrid, 256, 0, stream>>>(xw16, b3, startA, csr, out);
  k_logsm<<<aggGrid, 256, 0, stream>>>(out);
}

// Round 5
// 297.184 us; speedup vs baseline: 1.7192x; 1.1725x over previous
//
#include <hip/hip_runtime.h>
#include <cstdint>
#include <cstddef>

#define N_NODES 50000
#define BN_EPS 1e-5f
#define NPB 256                         // nodes per bucket
#define NB ((N_NODES + NPB - 1) / NPB)  // 196 buckets
#define EPB 2048                        // edges per build block

typedef unsigned int uint32;
typedef unsigned short ushort;

typedef short bf16x8 __attribute__((ext_vector_type(8)));
typedef float f32x4 __attribute__((ext_vector_type(4)));

// ---------------- helpers ----------------

__device__ inline ushort bf16rn(float f) {
  unsigned int u = __float_as_uint(f);
  u += 0x7fffu + ((u >> 16) & 1u);
  return (ushort)(u >> 16);
}
__device__ inline float unbf(uint32 u) { return __uint_as_float(u << 16); }
__device__ inline float lo16(uint32 u) { return __uint_as_float(u << 16); }
__device__ inline float hi16(uint32 u) { return __uint_as_float(u & 0xffff0000u); }
__device__ inline uint32 pack2(float a, float b) {
  return (uint32)bf16rn(a) | ((uint32)bf16rn(b) << 16);
}

// ---------------- weight convert: Wt[c][k] = bf16(W[k][c]) ----------------

__global__ __launch_bounds__(256) void k_cvtW(const float* __restrict__ W,
    ushort* __restrict__ Wt, int Fout) {
  int gid = blockIdx.x * 256 + threadIdx.x;
  if (gid >= Fout * 128) return;
  int c = gid >> 7, k = gid & 127;
  Wt[c * 128 + k] = bf16rn(W[(size_t)k * Fout + c]);
}

// ---------------- CSR build: binned two-phase ----------------

// per-bucket histogram; saves per-block hist for reuse in k_binA
__global__ __launch_bounds__(256) void k_ehist(const int* __restrict__ dst, int E,
    int* __restrict__ histB, int* __restrict__ hists) {
  __shared__ int h[NB];
  for (int i = threadIdx.x; i < NB; i += 256) h[i] = 0;
  __syncthreads();
  int base = blockIdx.x * EPB;
  for (int i = threadIdx.x; i < EPB; i += 256) {
    int e = base + i;
    if (e < E) atomicAdd(&h[dst[e] >> 8], 1);
  }
  __syncthreads();
  for (int i = threadIdx.x; i < NB; i += 256) {
    int v = h[i];
    hists[blockIdx.x * NB + i] = v;
    if (v) atomicAdd(&histB[i], v);
  }
}

__global__ void k_prefix(const int* __restrict__ histB, int E,
                         int* __restrict__ rbase, int* __restrict__ cbase,
                         int* __restrict__ start) {
  if (threadIdx.x == 0 && blockIdx.x == 0) {
    int r = 0, c = 0;
    for (int b = 0; b < NB; ++b) {
      int npb = (b == NB - 1) ? (N_NODES - b * NPB) : NPB;
      rbase[b] = r; cbase[b] = c;
      r += histB[b]; c += histB[b] + npb;
    }
    rbase[NB] = r;
    start[N_NODES] = c;   // == E + N_NODES
  }
}

// phase A: claim runs from saved hist, single pass binning edges
__global__ __launch_bounds__(256) void k_binA(const int* __restrict__ src,
    const int* __restrict__ dst, const float* __restrict__ ew, int E,
    const int* __restrict__ rbase, const int* __restrict__ hists,
    int* __restrict__ gcur, uint2* __restrict__ bins) {
  __shared__ int gb[NB], cur[NB];
  for (int i = threadIdx.x; i < NB; i += 256) {
    int hv = hists[blockIdx.x * NB + i];
    cur[i] = 0;
    gb[i] = hv ? (rbase[i] + atomicAdd(&gcur[i], hv)) : 0;
  }
  __syncthreads();
  int base = blockIdx.x * EPB;
  for (int i = threadIdx.x; i < EPB; i += 256) {
    int e = base + i;
    if (e < E) {
      int d = dst[e];
      int g = d >> 8;
      int p = gb[g] + atomicAdd(&cur[g], 1);
      bins[p] = make_uint2((uint32)src[e] | ((uint32)(d & 255) << 16),
                           __float_as_uint(ew[e]));
    }
  }
}

// phase B: one block per bucket: local hist+scan, start/dinv/self, scatter csr
__global__ __launch_bounds__(256) void k_binB(const uint2* __restrict__ bins,
    const int* __restrict__ rbase, const int* __restrict__ cbase,
    int* __restrict__ start, float* __restrict__ dinv, uint32* __restrict__ csr) {
  __shared__ int h[256], cur[256], ofs[256], sc[256];
  __shared__ float deg[256];
  int tid = threadIdx.x;
  int b = blockIdx.x;
  int node0 = b << 8;
  int npb = min(NPB, N_NODES - node0);
  h[tid] = 0; deg[tid] = 1.0f;   // self-loop weight
  __syncthreads();
  int r0 = rbase[b], r1 = rbase[b + 1];
  for (int i = r0 + tid; i < r1; i += 256) {
    uint2 rec = bins[i];
    int dl = (rec.x >> 16) & 255;
    atomicAdd(&h[dl], 1);
    atomicAdd(&deg[dl], __uint_as_float(rec.y));
  }
  __syncthreads();
  int v = (tid < npb) ? 1 + h[tid] : 0;
  sc[tid] = v;
  __syncthreads();
  for (int off = 1; off < 256; off <<= 1) {
    int a = (tid >= off) ? sc[tid - off] : 0;
    __syncthreads();
    sc[tid] += a;
    __syncthreads();
  }
  int cb = cbase[b];
  if (tid < npb) {
    int segBase = cb + sc[tid] - v;
    int node = node0 + tid;
    start[node] = segBase;
    csr[segBase] = (0x3F80u << 16) | (uint32)node;   // self: w=1.0
    dinv[node] = rsqrtf(deg[tid]);
    ofs[tid] = segBase + 1;
    cur[tid] = 0;
  }
  __syncthreads();
  for (int i = r0 + tid; i < r1; i += 256) {
    uint2 rec = bins[i];
    int dl = (rec.x >> 16) & 255;
    int p = ofs[dl] + atomicAdd(&cur[dl], 1);
    csr[p] = ((uint32)bf16rn(__uint_as_float(rec.y)) << 16) | (rec.x & 0xffff);
  }
}

// rewrite csr weights in place: w <- w * dinv[src] * dinv[node]
__global__ __launch_bounds__(256) void k_wnorm(uint32* __restrict__ csr,
    const int* __restrict__ start, const float* __restrict__ dinv) {
  int lane = threadIdx.x & 15;
  int node = blockIdx.x * 16 + (threadIdx.x >> 4);
  if (node >= N_NODES) return;
  float di = dinv[node];
  int e0 = start[node], e1 = start[node + 1];
  for (int e = e0 + lane; e < e1; e += 16) {
    uint32 c = csr[e];
    int s = c & 0xffff;
    float w = unbf(c >> 16) * dinv[s] * di;
    csr[e] = ((uint32)bf16rn(w) << 16) | (uint32)s;
  }
}

// ---------------- MFMA GEMM: out16[N,Fout] = act(X)[N,128] @ W[128,Fout] ----------------
// Wt is bf16 [Fout][128] (transposed). BNT = number of 16-col tiles (8 -> 128, 3 -> 48>=40).
// XT = float (layer 1) or ushort bf16. ssb: act(x)_f = max(0, x*ssb[f]+ssb[128+f]).

template <int BNT, typename XT>
__global__ __launch_bounds__(256) void k_mfma(const XT* __restrict__ X,
    const ushort* __restrict__ Wt, const float* __restrict__ ssb,
    ushort* __restrict__ out16, int Fout) {
  __shared__ ushort Xs[64][136];
  __shared__ ushort Bs[BNT * 16][136];
  int tid = threadIdx.x;
  int r0 = blockIdx.x * 64;

  // stage Bs[col][k] from Wt (16B vectors)
  for (int idx = tid; idx < BNT * 16 * 16; idx += 256) {
    int col = idx >> 4;
    int kk = (idx & 15) * 8;
    uint4 v = make_uint4(0, 0, 0, 0);
    if (col < Fout)
      v = *reinterpret_cast<const uint4*>(&Wt[(size_t)col * 128 + kk]);
    *reinterpret_cast<uint4*>(&Bs[col][kk]) = v;
  }

  // stage Xs[row][k] (convert to bf16; optional BN+ReLU)
  if (sizeof(XT) == 4) {
    const float* Xf = reinterpret_cast<const float*>(X);
    for (int idx = tid; idx < 2048; idx += 256) {
      int row = idx >> 5;
      int kk = (idx & 31) * 4;
      int gr = r0 + row;
      float4 v = make_float4(0.f, 0.f, 0.f, 0.f);
      if (gr < N_NODES)
        v = *reinterpret_cast<const float4*>(&Xf[(size_t)gr * 128 + kk]);
      ushort4 o;
      o.x = bf16rn(v.x); o.y = bf16rn(v.y); o.z = bf16rn(v.z); o.w = bf16rn(v.w);
      *reinterpret_cast<ushort4*>(&Xs[row][kk]) = o;
    }
  } else {
    const ushort* X16 = reinterpret_cast<const ushort*>(X);
    for (int idx = tid; idx < 1024; idx += 256) {
      int row = idx >> 4;
      int kk = (idx & 15) * 8;
      int gr = r0 + row;
      uint4 v = make_uint4(0, 0, 0, 0);
      if (gr < N_NODES)
        v = *reinterpret_cast<const uint4*>(&X16[(size_t)gr * 128 + kk]);
      if (ssb) {
        float f[8] = { lo16(v.x), hi16(v.x), lo16(v.y), hi16(v.y),
                       lo16(v.z), hi16(v.z), lo16(v.w), hi16(v.w) };
        float4 sc0 = *reinterpret_cast<const float4*>(&ssb[kk]);
        float4 sc1 = *reinterpret_cast<const float4*>(&ssb[kk + 4]);
        float4 sh0 = *reinterpret_cast<const float4*>(&ssb[128 + kk]);
        float4 sh1 = *reinterpret_cast<const float4*>(&ssb[128 + kk + 4]);
        f[0] = fmaxf(0.f, f[0] * sc0.x + sh0.x);
        f[1] = fmaxf(0.f, f[1] * sc0.y + sh0.y);
        f[2] = fmaxf(0.f, f[2] * sc0.z + sh0.z);
        f[3] = fmaxf(0.f, f[3] * sc0.w + sh0.w);
        f[4] = fmaxf(0.f, f[4] * sc1.x + sh1.x);
        f[5] = fmaxf(0.f, f[5] * sc1.y + sh1.y);
        f[6] = fmaxf(0.f, f[6] * sc1.z + sh1.z);
        f[7] = fmaxf(0.f, f[7] * sc1.w + sh1.w);
        v.x = pack2(f[0], f[1]); v.y = pack2(f[2], f[3]);
        v.z = pack2(f[4], f[5]); v.w = pack2(f[6], f[7]);
      }
      *reinterpret_cast<uint4*>(&Xs[row][kk]) = v;
    }
  }
  __syncthreads();

  int lane = tid & 63, wav = tid >> 6;
  int lrow = lane & 15, lk = (lane >> 4) * 8;
  f32x4 acc[BNT];
  #pragma unroll
  for (int ct = 0; ct < BNT; ++ct) acc[ct] = (f32x4){0.f, 0.f, 0.f, 0.f};

  #pragma unroll
  for (int kc = 0; kc < 4; ++kc) {
    int k0 = kc * 32 + lk;
    bf16x8 a = *reinterpret_cast<const bf16x8*>(&Xs[wav * 16 + lrow][k0]);
    #pragma unroll
    for (int ct = 0; ct < BNT; ++ct) {
      bf16x8 b = *reinterpret_cast<const bf16x8*>(&Bs[ct * 16 + lrow][k0]);
      acc[ct] = __builtin_amdgcn_mfma_f32_16x16x32_bf16(a, b, acc[ct], 0, 0, 0);
    }
  }

  int orow = wav * 16 + (lane >> 4) * 4;
  #pragma unroll
  for (int ct = 0; ct < BNT; ++ct) {
    int gc = ct * 16 + lrow;
    if (gc >= Fout) continue;
    #pragma unroll
    for (int i = 0; i < 4; ++i) {
      int gr = r0 + orow + i;
      if (gr < N_NODES) out16[(size_t)gr * Fout + gc] = bf16rn(acc[ct][i]);
    }
  }
}

// ---------------- aggregation: 1 wave per node, 4 edges in flight ----------------

__global__ __launch_bounds__(256) void k_agg128c(const ushort* __restrict__ xw,
    const float* __restrict__ bias, const int* __restrict__ start,
    const uint32* __restrict__ csr, ushort* __restrict__ out16) {
  int lane = threadIdx.x & 63;
  int node = blockIdx.x * 4 + (threadIdx.x >> 6);
  if (node >= N_NODES) return;
  int sub = lane >> 4;
  int fl  = lane & 15;
  const uint4* rows = (const uint4*)xw;
  float acc[8] = {};
  int e0 = start[node], e1 = start[node + 1];
  for (int e = e0 + sub; e < e1; e += 4) {
    uint32 c = csr[e];
    float w = unbf(c >> 16);
    int s = c & 0xffff;
    uint4 v = rows[(size_t)s * 16 + fl];
    acc[0] += w * lo16(v.x); acc[1] += w * hi16(v.x);
    acc[2] += w * lo16(v.y); acc[3] += w * hi16(v.y);
    acc[4] += w * lo16(v.z); acc[5] += w * hi16(v.z);
    acc[6] += w * lo16(v.w); acc[7] += w * hi16(v.w);
  }
  #pragma unroll
  for (int k = 0; k < 8; ++k) acc[k] += __shfl_xor(acc[k], 16);
  #pragma unroll
  for (int k = 0; k < 8; ++k) acc[k] += __shfl_xor(acc[k], 32);
  if (sub == 0) {
    float4 b0 = ((const float4*)bias)[fl * 2];
    float4 b1 = ((const float4*)bias)[fl * 2 + 1];
    acc[0] += b0.x; acc[1] += b0.y; acc[2] += b0.z; acc[3] += b0.w;
    acc[4] += b1.x; acc[5] += b1.y; acc[6] += b1.z; acc[7] += b1.w;
    uint4 o;
    o.x = pack2(acc[0], acc[1]);
    o.y = pack2(acc[2], acc[3]);
    o.z = pack2(acc[4], acc[5]);
    o.w = pack2(acc[6], acc[7]);
    ((uint4*)out16)[(size_t)node * 16 + fl] = o;
  }
}

__global__ __launch_bounds__(256) void k_agg40c(const ushort* __restrict__ xw,
    const float* __restrict__ bias, const int* __restrict__ start,
    const uint32* __restrict__ csr, float* __restrict__ out) {
  int lane = threadIdx.x & 63;
  int node = blockIdx.x * 4 + (threadIdx.x >> 6);
  if (node >= N_NODES) return;
  int sub = lane >> 4;
  int fl  = lane & 15;
  bool active = fl < 10;
  int flc = active ? fl : 0;
  const uint2* rows = (const uint2*)xw;
  float acc[4] = {};
  int e0 = start[node], e1 = start[node + 1];
  for (int e = e0 + sub; e < e1; e += 4) {
    uint32 c = csr[e];
    float w = unbf(c >> 16);
    int s = c & 0xffff;
    uint2 v = rows[(size_t)s * 10 + flc];
    if (active) {
      acc[0] += w * lo16(v.x); acc[1] += w * hi16(v.x);
      acc[2] += w * lo16(v.y); acc[3] += w * hi16(v.y);
    }
  }
  #pragma unroll
  for (int k = 0; k < 4; ++k) acc[k] += __shfl_xor(acc[k], 16);
  #pragma unroll
  for (int k = 0; k < 4; ++k) acc[k] += __shfl_xor(acc[k], 32);
  if (sub == 0 && active) {
    float4 b = ((const float4*)bias)[fl];
    float4 o = make_float4(acc[0] + b.x, acc[1] + b.y, acc[2] + b.z, acc[3] + b.w);
    *reinterpret_cast<float4*>(&out[(size_t)node * 40 + fl * 4]) = o;
  }
}

// ---------------- batch norm stats (bf16 input) ----------------

__global__ __launch_bounds__(256) void k_bnstats16(const ushort* __restrict__ x,
    float* __restrict__ sums) {
  int f = threadIdx.x & 127;
  int half = threadIdx.x >> 7;
  float s = 0.f, sq = 0.f;
  for (int row = blockIdx.x * 2 + half; row < N_NODES; row += gridDim.x * 2) {
    float v = __uint_as_float(((uint32)x[(size_t)row * 128 + f]) << 16);
    s += v; sq += v * v;
  }
  __shared__ float ls[256], lq[256];
  ls[threadIdx.x] = s; lq[threadIdx.x] = sq;
  __syncthreads();
  if (half == 0) {
    s += ls[threadIdx.x + 128];
    sq += lq[threadIdx.x + 128];
    atomicAdd(&sums[f], s);
    atomicAdd(&sums[128 + f], sq);
  }
}

__global__ void k_bnfinal(const float* __restrict__ sums,
    const float* __restrict__ gamma, const float* __restrict__ beta,
    float* __restrict__ ssb) {
  int f = threadIdx.x;
  float inv_n = 1.0f / (float)N_NODES;
  float mu = sums[f] * inv_n;
  float var = sums[128 + f] * inv_n - mu * mu;
  if (var < 0.f) var = 0.f;
  float scale = gamma[f] * rsqrtf(var + BN_EPS);
  ssb[f] = scale;
  ssb[128 + f] = beta[f] - mu * scale;
}

// ---------------- log_softmax over 40 classes ----------------

__global__ __launch_bounds__(256) void k_logsm(float* __restrict__ io) {
  int lane = threadIdx.x & 63;
  int node = blockIdx.x * 4 + (threadIdx.x >> 6);
  if (node >= N_NODES) return;
  float v = (lane < 40) ? io[(size_t)node * 40 + lane] : -1e30f;
  float m = v;
  #pragma unroll
  for (int off = 32; off >= 1; off >>= 1) m = fmaxf(m, __shfl_xor(m, off));
  float e = (lane < 40) ? expf(v - m) : 0.f;
  float ssum = e;
  #pragma unroll
  for (int off = 32; off >= 1; off >>= 1) ssum += __shfl_xor(ssum, off);
  if (lane < 40) io[(size_t)node * 40 + lane] = v - m - logf(ssum);
}

// ---------------- launch ----------------

extern "C" void kernel_launch(void* const* d_in, const int* in_sizes, int n_in,
                              void* d_out, int out_size, void* d_ws, size_t ws_size,
                              hipStream_t stream) {
  const float* x   = (const float*)d_in[0];
  const int*   ei  = (const int*)d_in[1];
  const float* ew  = (const float*)d_in[2];
  const float* W1  = (const float*)d_in[3];
  const float* b1  = (const float*)d_in[4];
  const float* g1  = (const float*)d_in[5];
  const float* be1 = (const float*)d_in[6];
  const float* W2  = (const float*)d_in[7];
  const float* b2  = (const float*)d_in[8];
  const float* g2  = (const float*)d_in[9];
  const float* be2 = (const float*)d_in[10];
  const float* W3  = (const float*)d_in[11];
  const float* b3  = (const float*)d_in[12];
  float* out = (float*)d_out;
  int E = in_sizes[2];
  const int* src = ei;
  const int* dst = ei + E;
  int nblkA = (E + EPB - 1) / EPB;

  char* p = (char*)d_ws;
  auto alloc = [&](size_t bytes) {
    char* r = p; p += (bytes + 255) & ~(size_t)255; return r;
  };
  int*    histB  = (int*)   alloc((size_t)(NB + 1) * 4);
  int*    rbase  = (int*)   alloc((size_t)(NB + 1) * 4);
  int*    cbase  = (int*)   alloc((size_t)NB * 4);
  int*    gcur   = (int*)   alloc((size_t)NB * 4);
  int*    hists  = (int*)   alloc((size_t)nblkA * NB * 4);
  int*    startA = (int*)   alloc((size_t)(N_NODES + 1) * 4);
  float*  dinv   = (float*) alloc((size_t)N_NODES * 4);
  uint2*  bins   = (uint2*) alloc((size_t)E * 8);
  uint32* csr    = (uint32*)alloc((size_t)(E + N_NODES) * 4);
  float*  stats  = (float*) alloc(256 * 4);
  float*  ssb    = (float*) alloc(256 * 4);
  ushort* Wt1    = (ushort*)alloc((size_t)128 * 128 * 2);
  ushort* Wt2    = (ushort*)alloc((size_t)128 * 128 * 2);
  ushort* Wt3    = (ushort*)alloc((size_t)40 * 128 * 2);
  ushort* xw16   = (ushort*)alloc((size_t)N_NODES * 128 * 2);
  ushort* buf16  = (ushort*)alloc((size_t)N_NODES * 128 * 2);

  hipMemsetAsync(histB, 0, (size_t)(NB + 1) * 4, stream);
  hipMemsetAsync(gcur, 0, (size_t)NB * 4, stream);
  k_cvtW<<<64, 256, 0, stream>>>(W1, Wt1, 128);
  k_cvtW<<<64, 256, 0, stream>>>(W2, Wt2, 128);
  k_cvtW<<<20, 256, 0, stream>>>(W3, Wt3, 40);
  k_ehist<<<nblkA, 256, 0, stream>>>(dst, E, histB, hists);
  k_prefix<<<1, 64, 0, stream>>>(histB, E, rbase, cbase, startA);
  k_binA<<<nblkA, 256, 0, stream>>>(src, dst, ew, E, rbase, hists, gcur, bins);
  k_binB<<<NB, 256, 0, stream>>>(bins, rbase, cbase, startA, dinv, csr);
  k_wnorm<<<(N_NODES + 15) / 16, 256, 0, stream>>>(csr, startA, dinv);

  int gemmGrid = (N_NODES + 63) / 64;   // 782
  int aggGrid = (N_NODES + 3) / 4;

  // layer 1
  k_mfma<8, float><<<gemmGrid, 256, 0, stream>>>(x, Wt1, nullptr, xw16, 128);
  k_agg128c<<<aggGrid, 256, 0, stream>>>(xw16, b1, startA, csr, buf16);
  hipMemsetAsync(stats, 0, 256 * 4, stream);
  k_bnstats16<<<256, 256, 0, stream>>>(buf16, stats);
  k_bnfinal<<<1, 128, 0, stream>>>(stats, g1, be1, ssb);

  // layer 2 (BN1+ReLU fused into GEMM staging)
  k_mfma<8, ushort><<<gemmGrid, 256, 0, stream>>>(buf16, Wt2, ssb, xw16, 128);
  k_agg128c<<<aggGrid, 256, 0, stream>>>(xw16, b2, startA, csr, buf16);
  hipMemsetAsync(stats, 0, 256 * 4, stream);
  k_bnstats16<<<256, 256, 0, stream>>>(buf16, stats);
  k_bnfinal<<<1, 128, 0, stream>>>(stats, g2, be2, ssb);

  // layer 3 (BN2+ReLU fused into GEMM staging)
  k_mfma<3, ushort><<<gemmGrid, 256, 0, stream>>>(buf16, Wt3, ssb, xw16, 40);
  k_agg40c<<<aggGrid, 256, 0, stream>>>(xw16, b3, startA, csr, out);
  k_logsm<<<aggGrid, 256, 0, stream>>>(out);
}